// Round 10
// baseline (7153.597 us; speedup 1.0000x reference)
//
#include <hip/hip_runtime.h>

#define NB 4096   // batch
#define NH 1024   // hidden
#define NE 512    // embedding dim
#define NV 23     // vocab
#define NT 64     // seq len
#define NL 144    // latent+cond
#define PADV 21
#define SOSV 22

typedef unsigned short u16;
typedef __attribute__((ext_vector_type(16))) float f32x16;
typedef __attribute__((ext_vector_type(8))) __bf16 bf16x8;
typedef __attribute__((ext_vector_type(8))) unsigned short u16x8;

__device__ __forceinline__ u16 f2bf(float x) {
  unsigned u = __float_as_uint(x);
  u += 0x7FFFu + ((u >> 16) & 1u);   // RNE to bf16
  return (u16)(u >> 16);
}
__device__ __forceinline__ float bf2f(u16 h) {
  return __uint_as_float(((unsigned)h) << 16);
}

// h image layout: [mt=m>>8][ks=j>>5][q=(j>>3)&3][row=m&255][e=j&7]
__device__ __forceinline__ size_t hidx(int m, int j) {
  return ((size_t)(((m >> 8) * 32 + (j >> 5)) * 4 + ((j >> 3) & 3)) * 2048)
         + (size_t)((m & 255) * 8) + (j & 7);
}

// ---------------------------------------------------------------------------
// prep: split W_hh into bf16 hi/lo images (g-major rows for 32x32 MFMA), zero c,
// SOS tokens.  W image: [jt=j>>6][ks=k>>5][q=(k>>3)&3][row=g*64+(j&63)][e=k&7]
__global__ void prep_kernel(const float* __restrict__ Whh, u16* __restrict__ Whi,
                            u16* __restrict__ Wlo, float* __restrict__ c,
                            int* __restrict__ tok) {
  int i = blockIdx.x * 256 + threadIdx.x;   // 4M threads = 4*NH*NH = NB*NH
  float wv = Whh[i];
  u16 hi = f2bf(wv);
  u16 lo = f2bf(wv - bf2f(hi));
  const int nw = i >> 10, k = i & 1023;
  const int g = nw >> 10, jcol = nw & 1023;
  const int jt = jcol >> 6, jl = jcol & 63;
  const int row = g * 64 + jl;
  const size_t oi = ((size_t)((jt * 32 + (k >> 5)) * 4 + ((k >> 3) & 3)) * 2048)
                    + (size_t)(row * 8) + (k & 7);
  Whi[oi] = hi;
  Wlo[oi] = lo;
  c[i] = 0.0f;
  if (i < NB) tok[i] = SOSV;
}

// ---------------------------------------------------------------------------
__global__ void exw_kernel(const float* __restrict__ emb, const float* __restrict__ Wih,
                           const float* __restrict__ bih, const float* __restrict__ bhh,
                           float* __restrict__ ExW) {
  __shared__ float Es[NE];
  const int v = blockIdx.y;
  const int n = blockIdx.x * 256 + threadIdx.x;
  for (int k = threadIdx.x; k < NE; k += 256)
    Es[k] = (v == PADV) ? 0.0f : emb[v * NE + k];
  __syncthreads();
  float s = bih[n] + bhh[n];
  const float* wr = Wih + (long)n * NE;
  for (int k = 0; k < NE; ++k) s = fmaf(Es[k], wr[k], s);
  ExW[v * (4 * NH) + n] = s;
}

// ---------------------------------------------------------------------------
__global__ void h0_kernel(const float* __restrict__ z, const float* __restrict__ cnd,
                          const float* __restrict__ Wlh, const float* __restrict__ blh,
                          u16* __restrict__ hhi, u16* __restrict__ hlo) {
  __shared__ float zc[8][NL];
  const int b0 = blockIdx.y * 8;
  const int j = blockIdx.x * 256 + threadIdx.x;
  for (int idx = threadIdx.x; idx < 8 * NL; idx += 256) {
    int bi = idx / NL, k = idx % NL;
    zc[bi][k] = (k < 128) ? z[(long)(b0 + bi) * 128 + k]
                          : cnd[(long)(b0 + bi) * 16 + (k - 128)];
  }
  __syncthreads();
  float acc[8];
  const float bj = blh[j];
#pragma unroll
  for (int bi = 0; bi < 8; ++bi) acc[bi] = bj;
  const float* wr = Wlh + (long)j * NL;
  for (int k = 0; k < NL; ++k) {
    float wv = wr[k];
#pragma unroll
    for (int bi = 0; bi < 8; ++bi) acc[bi] = fmaf(wv, zc[bi][k], acc[bi]);
  }
#pragma unroll
  for (int bi = 0; bi < 8; ++bi) {
    size_t idx = hidx(b0 + bi, j);
    u16 hi = f2bf(acc[bi]);
    hhi[idx] = hi;
    hlo[idx] = f2bf(acc[bi] - bf2f(hi));
  }
}

// ---------------------------------------------------------------------------
__device__ __forceinline__ void stage8(const u16* __restrict__ src, u16* dst) {
#pragma unroll
  for (int i = 0; i < 8; ++i)
    __builtin_amdgcn_global_load_lds(
        (const __attribute__((address_space(1))) void*)(src + i * 512),
        (__attribute__((address_space(3))) void*)(dst + i * 512), 16, 0, 0);
}

// Fused gates GEMM (split-bf16, 3 MFMA products, 32x32x16) + LSTM cell epilogue.
// r2 skeleton: 512 thr (8 waves = 4 wm x 2 wn), tile 256 m x (64 j x 4 g), BK=32,
// 128 KiB dbuf LDS, single compiler-scheduled barrier per iter.
// 32x32 MFMAs with (product,(g,mi)) round-robin: dependent acc reuse distance = 8.
__global__ __launch_bounds__(512, 2)
void gates_cell_kernel(const u16* __restrict__ Whi, const u16* __restrict__ Wlo,
                       const u16* __restrict__ hhi_in, const u16* __restrict__ hlo_in,
                       const float* __restrict__ ExW, const int* __restrict__ tok,
                       float* __restrict__ c, u16* __restrict__ hhi_out,
                       u16* __restrict__ hlo_out) {
  __shared__ u16 lds[65536];   // [4 mats][2 dbuf][8192] : Ahi Alo Bhi Blo

  const int bid = blockIdx.x;                   // 256 blocks = 16 mt x 16 jt
  const int swz = (bid & 7) * 32 + (bid >> 3);  // XCD x owns jt {2x,2x+1}
  const int jt = swz >> 4;
  const int mt = swz & 15;
  const int m0 = mt << 8;
  const int j0 = jt << 6;

  const int tid = threadIdx.x;
  const int w = tid >> 6, l = tid & 63;
  const int wm = w >> 1, wn = w & 1;            // wave tile: 64 m x (32 j x 4 g)
  const int col = l & 31, h5 = l >> 5;

  // staging role (r2 verbatim): mat = w>>1, hf = w&1 picks 4KB half of 8KB tile
  const int mat = w >> 1, hf = w & 1;
  const u16* simg = (mat == 0) ? hhi_in : (mat == 1) ? hlo_in : (mat == 2) ? Whi : Wlo;
  const size_t sbase = ((mat < 2) ? ((size_t)mt * 262144) : ((size_t)jt * 262144))
                       + (size_t)hf * 4096 + (size_t)l * 8;
  const u16* sit = simg + sbase;
  u16* dwave = (u16*)lds + mat * 16384 + hf * 4096;

  f32x16 acc[2][4];   // [mi (32m)][g]
#pragma unroll
  for (int mi = 0; mi < 2; ++mi)
#pragma unroll
    for (int g = 0; g < 4; ++g)
#pragma unroll
      for (int r = 0; r < 16; ++r) acc[mi][g][r] = 0.f;

  stage8(sit, dwave);           // prologue: stage ks=0 into buf 0
  __syncthreads();

  for (int ks = 0; ks < 32; ++ks) {
    const int buf = ks & 1;
    if (ks < 31) stage8(sit + (size_t)(ks + 1) * 8192, dwave + (buf ^ 1) * 8192);

    const u16* abase = lds + buf * 8192;           // Ahi (Alo at +16384)
    const u16* bbase = lds + 32768 + buf * 8192;   // Bhi (Blo at +16384)

#pragma unroll
    for (int kk = 0; kk < 2; ++kk) {               // two K=16 halves of BK=32
      const int ko = (kk * 2 + h5) * 2048;         // lane's k-octet block
      bf16x8 ah[2], al[2], bh[4], bl[4];
#pragma unroll
      for (int mi = 0; mi < 2; ++mi) {
        const int ao = ko + (wm * 64 + mi * 32 + col) * 8;
        ah[mi] = *reinterpret_cast<const bf16x8*>(abase + ao);
        al[mi] = *reinterpret_cast<const bf16x8*>(abase + 16384 + ao);
      }
#pragma unroll
      for (int g = 0; g < 4; ++g) {
        const int bo = ko + (g * 64 + wn * 32 + col) * 8;
        bh[g] = *reinterpret_cast<const bf16x8*>(bbase + bo);
        bl[g] = *reinterpret_cast<const bf16x8*>(bbase + 16384 + bo);
      }
      // product hi*hi  (8 independent accs per pass)
#pragma unroll
      for (int g = 0; g < 4; ++g)
#pragma unroll
        for (int mi = 0; mi < 2; ++mi)
          acc[mi][g] = __builtin_amdgcn_mfma_f32_32x32x16_bf16(ah[mi], bh[g], acc[mi][g], 0, 0, 0);
      // product hi*lo
#pragma unroll
      for (int g = 0; g < 4; ++g)
#pragma unroll
        for (int mi = 0; mi < 2; ++mi)
          acc[mi][g] = __builtin_amdgcn_mfma_f32_32x32x16_bf16(ah[mi], bl[g], acc[mi][g], 0, 0, 0);
      // product lo*hi
#pragma unroll
      for (int g = 0; g < 4; ++g)
#pragma unroll
        for (int mi = 0; mi < 2; ++mi)
          acc[mi][g] = __builtin_amdgcn_mfma_f32_32x32x16_bf16(al[mi], bh[g], acc[mi][g], 0, 0, 0);
    }
    __syncthreads();   // drains stage (vmcnt0) + lgkm before dbuf reuse
  }

  // epilogue: + ExW[token], LSTM cell (fp32), write h hi/lo in image layout
  // C/D layout (32x32): col = lane&31, row = (reg&3) + 8*(reg>>2) + 4*(lane>>5)
  const int j = j0 + wn * 32 + col;
#pragma unroll
  for (int mi = 0; mi < 2; ++mi) {
#pragma unroll
    for (int r = 0; r < 16; ++r) {
      const int row = (r & 3) + ((r >> 2) << 3) + (h5 << 2);
      const int m = m0 + wm * 64 + mi * 32 + row;
      const int tk = tok[m];
      const float* exr = ExW + (size_t)tk * 4096;
      const float gi = acc[mi][0][r] + exr[j];
      const float gf = acc[mi][1][r] + exr[NH + j];
      const float gg = acc[mi][2][r] + exr[2 * NH + j];
      const float go = acc[mi][3][r] + exr[3 * NH + j];
      const float i_ = 1.0f / (1.0f + expf(-gi));
      const float f_ = 1.0f / (1.0f + expf(-gf));
      const float g_ = tanhf(gg);
      const float o_ = 1.0f / (1.0f + expf(-go));
      const size_t cidx = (size_t)m * NH + j;
      const float cn = f_ * c[cidx] + i_ * g_;
      c[cidx] = cn;
      const float hn = o_ * tanhf(cn);
      const u16 hi = f2bf(hn);
      const size_t oidx = hidx(m, j);
      hhi_out[oidx] = hi;
      hlo_out[oidx] = f2bf(hn - bf2f(hi));
    }
  }
}

// ---------------------------------------------------------------------------
// logits = h @ W_out^T + b_out ; 8 batch rows per block (amortize W_out reads).
__global__ __launch_bounds__(256)
void logits_kernel(const u16* __restrict__ hhi, const u16* __restrict__ hlo,
                   const float* __restrict__ Wout, const float* __restrict__ bout,
                   float* __restrict__ out, int* __restrict__ tok, int t) {
  __shared__ float hs[8][NH];
  __shared__ float part[8][24][8];
  __shared__ float lg[8][24];
  const int b0 = blockIdx.x * 8;
  const int tid = threadIdx.x;
  for (int ci = tid; ci < 1024; ci += 256) {
    const int bi = ci >> 7, cj = ci & 127;
    const int m = b0 + bi;
    const int ks = cj >> 2, qq = cj & 3;
    const size_t base = ((size_t)(((m >> 8) * 32 + ks) * 4 + qq) * 2048)
                        + (size_t)((m & 255) * 8);
    const u16x8 vh = *reinterpret_cast<const u16x8*>(hhi + base);
    const u16x8 vl = *reinterpret_cast<const u16x8*>(hlo + base);
    const int kb = ks * 32 + qq * 8;
#pragma unroll
    for (int e = 0; e < 8; ++e) hs[bi][kb + e] = bf2f(vh[e]) + bf2f(vl[e]);
  }
  __syncthreads();
  const int v = tid & 31, kc = tid >> 5;
  if (v < NV) {
    float s[8];
#pragma unroll
    for (int bi = 0; bi < 8; ++bi) s[bi] = 0.f;
    const float* wr = Wout + (long)v * NH + kc * 128;
    const int kb = kc * 128;
    for (int k = 0; k < 128; ++k) {
      float wv = wr[k];
#pragma unroll
      for (int bi = 0; bi < 8; ++bi) s[bi] = fmaf(wv, hs[bi][kb + k], s[bi]);
    }
#pragma unroll
    for (int bi = 0; bi < 8; ++bi) part[kc][v][bi] = s[bi];
  }
  __syncthreads();
  if (tid < NV * 8) {
    const int vv = tid >> 3, bi = tid & 7;
    float s = bout[vv];
#pragma unroll
    for (int k = 0; k < 8; ++k) s += part[k][vv][bi];
    lg[bi][vv] = s;
    out[((long)(b0 + bi) * NT + t) * NV + vv] = s;
  }
  __syncthreads();
  if (tid < 8) {
    float best = lg[tid][0];
    int bv = 0;
    for (int vv = 1; vv < NV; ++vv) {
      float x = lg[tid][vv];
      if (x > best) { best = x; bv = vv; }   // strict > : first-max like np.argmax
    }
    tok[b0 + tid] = bv;
  }
}

// ---------------------------------------------------------------------------
extern "C" void kernel_launch(void* const* d_in, const int* in_sizes, int n_in,
                              void* d_out, int out_size, void* d_ws, size_t ws_size,
                              hipStream_t stream) {
  const float* z    = (const float*)d_in[0];
  const float* cnd  = (const float*)d_in[1];
  const float* emb  = (const float*)d_in[2];
  const float* Wlh  = (const float*)d_in[3];
  const float* blh  = (const float*)d_in[4];
  const float* Wih  = (const float*)d_in[5];
  const float* Whh  = (const float*)d_in[6];
  const float* bih  = (const float*)d_in[7];
  const float* bhh  = (const float*)d_in[8];
  const float* Wout = (const float*)d_in[9];
  const float* bout = (const float*)d_in[10];
  float* out = (float*)d_out;

  char* ws = (char*)d_ws;
  size_t off = 0;
  auto alloc = [&](size_t bytes) -> void* {
    off = (off + 255) & ~(size_t)255;
    void* p = ws + off;
    off += bytes;
    return p;
  };
  u16* Whi = (u16*)alloc((size_t)4 * NH * NH * 2);
  u16* Wlo = (u16*)alloc((size_t)4 * NH * NH * 2);
  float* ExW = (float*)alloc((size_t)NV * 4 * NH * 4);
  u16* hhi0 = (u16*)alloc((size_t)NB * NH * 2);
  u16* hhi1 = (u16*)alloc((size_t)NB * NH * 2);
  u16* hlo0 = (u16*)alloc((size_t)NB * NH * 2);
  u16* hlo1 = (u16*)alloc((size_t)NB * NH * 2);
  float* cbuf = (float*)alloc((size_t)NB * NH * 4);
  int* tokb = (int*)alloc((size_t)NB * 4);
  u16* hhi[2] = {hhi0, hhi1};
  u16* hlo[2] = {hlo0, hlo1};

  prep_kernel<<<dim3((4 * NH * NH) / 256), dim3(256), 0, stream>>>(Whh, Whi, Wlo, cbuf, tokb);
  exw_kernel<<<dim3((4 * NH) / 256, NV), dim3(256), 0, stream>>>(emb, Wih, bih, bhh, ExW);
  h0_kernel<<<dim3(NH / 256, NB / 8), dim3(256), 0, stream>>>(z, cnd, Wlh, blh, hhi[0], hlo[0]);

  int p = 0;
  for (int t = 0; t < NT; ++t) {
    gates_cell_kernel<<<dim3(256), dim3(512), 0, stream>>>(
        Whi, Wlo, hhi[p], hlo[p], ExW, tokb, cbuf, hhi[p ^ 1], hlo[p ^ 1]);
    logits_kernel<<<dim3(NB / 8), dim3(256), 0, stream>>>(
        hhi[p ^ 1], hlo[p ^ 1], Wout, bout, out, tokb, t);
    p ^= 1;
  }
}